// Round 1
// baseline (277.267 us; speedup 1.0000x reference)
//
#include <hip/hip_runtime.h>

// KAN conv feature extractor, fully fused: one workgroup (640 thr, 10 waves) per batch element.
// conv1 3x3 (1->5) + maxpool2 -> conv2 5x5 (5->5) -> conv3 3x3 (5->2) -> FC(98->200)
// Activations stored in LDS as fp16 "records" of 12 halves (24B, 8B-aligned):
// [silu, B0..B7, 0, pad, pad]. Inner products via v_dot2_f32_f16 (fp32 accumulate).
// Weights pre-packed to fp16 10-half records in d_ws; weight indices wave-uniform -> s_load.
// This revision: conv2/conv3 parallelized over (channel, position) with wave-uniform
// channel (readfirstlane) + LDS channel-reduce; closed-form 4-tap cardinal B-spline
// (only 4 bases are nonzero on a uniform knot grid) instead of Cox-de Boor.

typedef _Float16 h2 __attribute__((ext_vector_type(2)));
typedef unsigned int uint_t;
typedef unsigned long long u64;

__device__ __forceinline__ h2 as_h2(uint_t u) { union { uint_t u; h2 h; } c; c.u = u; return c.h; }
__device__ __forceinline__ uint_t pk(float a, float b) {
    h2 v; v[0] = (_Float16)a; v[1] = (_Float16)b;
    union { h2 h; uint_t u; } c; c.h = v; return c.u;
}

__device__ __forceinline__ float fdot2f(h2 a, h2 b, float c) {
#if __has_builtin(__builtin_amdgcn_fdot2)
    return __builtin_amdgcn_fdot2(a, b, c, false);
#else
    return c + (float)a[0] * (float)b[0] + (float)a[1] * (float)b[1];
#endif
}

__device__ __forceinline__ float silu_f(float v) {
    return v / (1.0f + __expf(-v));
}

// Transform value v -> fp16 record [silu, B0..B7, 0] at p (halves, 8B-aligned).
// Uniform-knot cubic B-spline: grid[j] = (j-3)*0.4 - 1, j=0..11; support [-2.2, 2.2).
// Only 4 bases nonzero: for cell c = floor((v+2.2)/0.4), u = frac, bases j=c-3..c get
// N(u+3)=(1-u)^3/6, N(u+2)=(3u^3-6u^2+4)/6, N(u+1)=(-3u^3+3u^2+3u+1)/6, N(u)=u^3/6.
// Pack the 4 halves [N3,N2,N1,N0] and shift into the 8-slot window at half (c-3);
// out-of-range slots truncate naturally (matches reference zero bases).
__device__ __forceinline__ void write_rec(_Float16* p, float v) {
    float s  = silu_f(v);
    float t  = (v + 2.2f) * 2.5f;
    float cf = floorf(t);
    int   c  = (int)cf;
    float u  = t - cf;
    float u2 = u * u, u3 = u2 * u;
    float w  = 1.0f - u;
    const float k6 = 0.16666667f;
    float n0 = k6 * u3;
    float n1 = k6 * (-3.0f * u3 + 3.0f * u2 + 3.0f * u + 1.0f);
    float n2 = k6 * (3.0f * u3 - 6.0f * u2 + 4.0f);
    float n3 = k6 * (w * w * w);
    u64 H = ((u64)pk(n1, n0) << 32) | (u64)pk(n3, n2);   // halves [n3,n2,n1,n0]
    if ((unsigned)c > 10u) H = 0;                        // v outside [-2.2,2.2): all-zero bases
    int cc = c < 0 ? 0 : (c > 10 ? 10 : c);              // clamp so all shifts are in [0,63]
    int sh = (cc - 3) * 16;                              // half->bit offset in bases window
    u64 B0, B1;                                          // B0 = bases 0..3, B1 = bases 4..7
    if (sh >= 64)      { B0 = 0;           B1 = H << (sh - 64); }
    else if (sh > 0)   { B0 = H << sh;     B1 = H >> (64 - sh); }
    else if (sh == 0)  { B0 = H;           B1 = 0; }
    else               { B0 = H >> (-sh);  B1 = 0; }
    // record halves: [silu, b0..b7, 0, ...]
    u64    R0 = (B0 << 16) | (u64)pk(s, 0.0f);
    u64    R1 = (B0 >> 48) | (B1 << 16);
    uint_t R2 = (uint_t)(B1 >> 48);                      // [b7, 0]
    *(uint2*)(p)      = make_uint2((uint_t)R0, (uint_t)(R0 >> 32));
    *(uint2*)(p + 4)  = make_uint2((uint_t)R1, (uint_t)(R1 >> 32));
    *(uint_t*)(p + 8) = R2;
}

struct Rec { h2 a[5]; };
__device__ __forceinline__ Rec load_rec(const _Float16* p) {
    uint2  u0 = *(const uint2*)(p);
    uint2  u1 = *(const uint2*)(p + 4);
    uint_t u2 = *(const uint_t*)(p + 8);
    Rec r;
    r.a[0] = as_h2(u0.x); r.a[1] = as_h2(u0.y);
    r.a[2] = as_h2(u1.x); r.a[3] = as_h2(u1.y);
    r.a[4] = as_h2(u2);
    return r;
}

// d_ws layout: [0)      w16: fp16 weight records, 10 halves each:
//                        W1: rec (c*9+t), 45 recs   @ half 0
//                        W2: rec (o*125+c*25+di*5+dj), 625 recs @ half 450
//                        W3: rec (o*45+c*9+di*3+dj), 90 recs    @ half 6700
//              [15360)  fcwT: float [98][200] (transposed FC weights)
#define W2_OFF 450
#define W3_OFF 6700
#define FCWT_BYTE_OFF 15360

__global__ __launch_bounds__(256) void kan_prep(
    const float* __restrict__ wb1, const float* __restrict__ ws1,
    const float* __restrict__ wb2, const float* __restrict__ ws2,
    const float* __restrict__ wb3, const float* __restrict__ ws3,
    const float* __restrict__ fcw, _Float16* __restrict__ w16,
    float* __restrict__ fcwT)
{
    int gtid = blockIdx.x * 256 + threadIdx.x;
    int gstr = gridDim.x * 256;
    for (int i = gtid; i < 760; i += gstr) {
        const float *wb, *ws; int r;
        if (i < 45)       { wb = wb1; ws = ws1; r = i; }
        else if (i < 670) { wb = wb2; ws = ws2; r = i - 45; }
        else              { wb = wb3; ws = ws3; r = i - 670; }
        _Float16* p = w16 + i * 10;
        p[0] = (_Float16)wb[r];
#pragma unroll
        for (int g = 0; g < 8; ++g) p[1 + g] = (_Float16)ws[r * 8 + g];
        p[9] = (_Float16)0.0f;
    }
    for (int i = gtid; i < 19600; i += gstr) {
        int o = i / 98, j = i % 98;
        fcwT[j * 200 + o] = fcw[i];
    }
}

// LDS: smemA (fp16 records, overlaid): t1 [784][12]=9408h | t2 [169 pos][5c][12]=10140h
//      | t3 [81 pos][5o][12]=4860h.
//      smemB float[2048] (overlaid): P2h fp16 [5][676]=3380h | conv2 partials [5c][5o][81]
//      =2025f | conv3 partials [5c][2o][49]=490f | h3 f32 [98] @ +1024 | FC partials [200].
// Total ~27.8 KB -> 3 WG/CU (wave-limited: 3 x 10 waves = 30/32).
__global__ __launch_bounds__(640, 8) void kan_fused(
    const float* __restrict__ x,      // [B,1,28,28]
    const _Float16* __restrict__ w16, // packed weights (d_ws)
    const float* __restrict__ fcwT,   // [98][200]
    const float* __restrict__ fcb,    // [200]
    float* __restrict__ out)          // [B,200]
{
    __shared__ __align__(16) _Float16 smemA[10140];
    __shared__ __align__(16) float    smemB[2048];
    _Float16* P2h   = (_Float16*)smemB;  // [c][676] halves
    float*    part2 = smemB;             // [(c*5+o)*81 + pp]
    float*    part3 = smemB;             // [(c*2+o)*49 + pp]
    float*    h3f   = smemB + 1024;      // [98]
    float*    fcp2  = smemB;             // [200] FC upper-half partials

    const int b   = blockIdx.x;
    const int tid = threadIdx.x;

    // ---- Phase 1: transform input pixels -> t1 records -------------------
#pragma unroll 1
    for (int i = tid; i < 784; i += 640)
        write_rec(&smemA[i * 12], x[b * 784 + i]);
    __syncthreads();

    // ---- Phase 2: conv1 3x3 at every sub-position (26x26), 5 out ch ------
#pragma unroll 1
    for (int s = tid; s < 676; s += 640) {
        int y = s / 26, xx = s % 26;
        Rec r[9];
#pragma unroll
        for (int t = 0; t < 9; ++t)
            r[t] = load_rec(&smemA[((y + t / 3) * 28 + xx + t % 3) * 12]);
        float acc[5] = {0.f, 0.f, 0.f, 0.f, 0.f};
#pragma unroll
        for (int t = 0; t < 9; ++t) {
#pragma unroll
            for (int c = 0; c < 5; ++c) {
                const h2* w = (const h2*)(w16 + (c * 9 + t) * 10);
                float a = acc[c];
#pragma unroll
                for (int q = 0; q < 5; ++q) a = fdot2f(r[t].a[q], w[q], a);
                acc[c] = a;
            }
        }
#pragma unroll
        for (int c = 0; c < 5; ++c) P2h[c * 676 + s] = (_Float16)acc[c];
    }
    __syncthreads();

    // ---- Phase 3: maxpool2 + transform -> t2 records ---------------------
#pragma unroll 1
    for (int i = tid; i < 845; i += 640) {
        int c = i / 169, pp = i % 169;
        int ph = pp / 13, pw = pp % 13;
        const _Float16* q = P2h + c * 676 + (2 * ph) * 26 + 2 * pw;
        h2 a = as_h2(*(const uint_t*)q);
        h2 d = as_h2(*(const uint_t*)(q + 26));
        float m = fmaxf(fmaxf((float)a[0], (float)a[1]),
                        fmaxf((float)d[0], (float)d[1]));
        write_rec(&smemA[pp * 60 + c * 12], m);
    }
    __syncthreads();

    // ---- Phase 4: conv2 5x5, split (c, pos): c wave-uniform, one pass ----
    {
        int c  = __builtin_amdgcn_readfirstlane(tid >> 7);  // 0..4, SGPR
        int pp = tid & 127;
        if (pp < 81) {
            int y = pp / 9, xx = pp % 9;
            float acc[5] = {0.f, 0.f, 0.f, 0.f, 0.f};
#pragma unroll 1
            for (int di = 0; di < 5; ++di) {
                const _Float16* base = &smemA[((y + di) * 13 + xx) * 60 + c * 12];
                Rec r[5];
#pragma unroll
                for (int p = 0; p < 5; ++p) r[p] = load_rec(base + p * 60);
#pragma unroll
                for (int o = 0; o < 5; ++o) {
                    const h2* w = (const h2*)(w16 + (W2_OFF + (o * 125 + c * 25 + di * 5) * 10));
                    float a = acc[o];
#pragma unroll
                    for (int dj = 0; dj < 5; ++dj)
#pragma unroll
                        for (int q = 0; q < 5; ++q)
                            a = fdot2f(r[dj].a[q], w[dj * 5 + q], a);
                    acc[o] = a;
                }
            }
#pragma unroll
            for (int o = 0; o < 5; ++o) part2[(c * 5 + o) * 81 + pp] = acc[o];
        }
    }
    __syncthreads();

    // ---- Phase 4b: c-reduce + transform -> t3 records (fuses old phase 5)
    if (tid < 405) {
        int o = tid / 81, pp = tid % 81;
        float v = part2[(0 * 5 + o) * 81 + pp] + part2[(1 * 5 + o) * 81 + pp]
                + part2[(2 * 5 + o) * 81 + pp] + part2[(3 * 5 + o) * 81 + pp]
                + part2[(4 * 5 + o) * 81 + pp];
        write_rec(&smemA[pp * 60 + o * 12], v);
    }
    __syncthreads();

    // ---- Phase 5: conv3 3x3, split (c, pos): c wave-uniform --------------
    {
        int c  = __builtin_amdgcn_readfirstlane(tid >> 6);  // 0..9, SGPR
        int pp = tid & 63;
        if (c < 5 && pp < 49) {
            int y = pp / 7, xx = pp % 7;
            float acc[2] = {0.f, 0.f};
#pragma unroll 1
            for (int di = 0; di < 3; ++di) {
                const _Float16* base = &smemA[((y + di) * 9 + xx) * 60 + c * 12];
                Rec r[3];
#pragma unroll
                for (int p = 0; p < 3; ++p) r[p] = load_rec(base + p * 60);
#pragma unroll
                for (int o = 0; o < 2; ++o) {
                    const h2* w = (const h2*)(w16 + (W3_OFF + (o * 45 + c * 9 + di * 3) * 10));
                    float a = acc[o];
#pragma unroll
                    for (int dj = 0; dj < 3; ++dj)
#pragma unroll
                        for (int q = 0; q < 5; ++q)
                            a = fdot2f(r[dj].a[q], w[dj * 5 + q], a);
                    acc[o] = a;
                }
            }
            part3[(c * 2 + 0) * 49 + pp] = acc[0];
            part3[(c * 2 + 1) * 49 + pp] = acc[1];
        }
    }
    __syncthreads();

    // ---- Phase 5b: c-reduce -> h3 [98] -----------------------------------
    if (tid < 98) {
        int o = tid / 49, pp = tid % 49;
        float v = part3[(0 * 2 + o) * 49 + pp] + part3[(1 * 2 + o) * 49 + pp]
                + part3[(2 * 2 + o) * 49 + pp] + part3[(3 * 2 + o) * 49 + pp]
                + part3[(4 * 2 + o) * 49 + pp];
        h3f[tid] = v;
    }
    __syncthreads();

    // ---- Phase 6: FC [98] -> [200], split 2-way over j -------------------
    float own = 0.f;
    if (tid < 400) {
        int o  = (tid < 200) ? tid : tid - 200;
        int j0 = (tid < 200) ? 0 : 49;
        float a = 0.f;
#pragma unroll 7
        for (int j = j0; j < j0 + 49; ++j)
            a += fcwT[j * 200 + o] * h3f[j];   // h3f: same-address broadcast
        if (tid >= 200) fcp2[o] = a;
        own = a;
    }
    __syncthreads();
    if (tid < 200) out[b * 200 + tid] = fcb[tid] + own + fcp2[tid];
}

extern "C" void kernel_launch(void* const* d_in, const int* in_sizes, int n_in,
                              void* d_out, int out_size, void* d_ws, size_t ws_size,
                              hipStream_t stream) {
    const float* x   = (const float*)d_in[0];
    const float* wb1 = (const float*)d_in[1];
    const float* ws1 = (const float*)d_in[2];
    const float* wb2 = (const float*)d_in[3];
    const float* ws2 = (const float*)d_in[4];
    const float* wb3 = (const float*)d_in[5];
    const float* ws3 = (const float*)d_in[6];
    const float* fcw = (const float*)d_in[7];
    const float* fcb = (const float*)d_in[8];
    float* out = (float*)d_out;

    _Float16* w16  = (_Float16*)d_ws;
    float*    fcwT = (float*)((char*)d_ws + FCWT_BYTE_OFF);

    kan_prep<<<32, 256, 0, stream>>>(wb1, ws1, wb2, ws2, wb3, ws3, fcw, w16, fcwT);

    int B = in_sizes[0] / 784;  // 4096
    kan_fused<<<B, 640, 0, stream>>>(x, w16, fcwT, fcb, out);
}

// Round 2
// 206.825 us; speedup vs baseline: 1.3406x; 1.3406x over previous
//
#include <hip/hip_runtime.h>

// KAN conv feature extractor, fully fused: one workgroup (256 thr) per batch element.
// conv1 3x3 (1->5) + maxpool2 -> conv2 5x5 (5->5) -> conv3 3x3 (5->2) -> FC(98->200)
// Activations in LDS as fp16 "records" of 12 halves: [silu, B0..B7, 0, pad, pad].
// Inner products via v_dot2_f32_f16 (fp32 accumulate). Weights pre-packed fp16
// 10-half records in d_ws; weight indices wave-uniform -> s_load.
// R2: 256-thread geometry (5 WG/CU) + branchless closed-form cardinal B-spline
// + conv2/conv3 spread over all 4 waves (c wave-uniform via readfirstlane, LDS
// c-reduce) + 2-chain FC. Total issued dot2 unchanged; serial poles split.

typedef _Float16 h2 __attribute__((ext_vector_type(2)));
typedef unsigned int uint_t;
typedef unsigned long long u64;

__device__ __forceinline__ h2 as_h2(uint_t u) { union { uint_t u; h2 h; } c; c.u = u; return c.h; }
__device__ __forceinline__ uint_t pk(float a, float b) {
    h2 v; v[0] = (_Float16)a; v[1] = (_Float16)b;
    union { h2 h; uint_t u; } c; c.h = v; return c.u;
}

__device__ __forceinline__ float fdot2f(h2 a, h2 b, float c) {
#if __has_builtin(__builtin_amdgcn_fdot2)
    return __builtin_amdgcn_fdot2(a, b, c, false);
#else
    return c + (float)a[0] * (float)b[0] + (float)a[1] * (float)b[1];
#endif
}

__device__ __forceinline__ float silu_f(float v) {
    return v / (1.0f + __expf(-v));
}

// Transform value v -> fp16 record [silu, B0..B7, 0] at p (halves, 8B-aligned).
// Uniform-knot cubic B-spline, grid[j] = (j-3)*0.4 - 1. Only 4 bases nonzero:
// cell c = floor((v+2.2)/0.4), u = frac; bases j = c-3..c get
// {(1-u)^3, 3u^3-6u^2+4, -3u^3+3u^2+3u+1, u^3}/6. Scatter into the 8-slot window
// via a branchless 128-bit shift (all shift amounts &63 -> defined; selects are
// cndmask, no divergence). Out-of-range v -> all-zero bases (matches reference).
__device__ __forceinline__ void write_rec(_Float16* p, float v) {
    float s  = silu_f(v);
    float t  = (v + 2.2f) * 2.5f;
    float cf = floorf(t);
    int   c  = (int)cf;
    float u  = t - cf;
    float u2 = u * u, u3 = u2 * u;
    float w  = 1.0f - u;
    const float k6 = 0.16666667f;
    float n0 = k6 * u3;
    float n1 = k6 * (-3.0f * u3 + 3.0f * u2 + 3.0f * u + 1.0f);
    float n2 = k6 * (3.0f * u3 - 6.0f * u2 + 4.0f);
    float n3 = k6 * (w * w * w);
    u64 H = ((u64)pk(n1, n0) << 32) | (u64)pk(n3, n2);   // halves [n3,n2,n1,n0]
    if ((unsigned)c > 10u) H = 0;                        // outside [-2.2,2.2): zero bases
    int cc = c < 0 ? 0 : (c > 10 ? 10 : c);
    int L  = cc * 16 - 48;                               // window shift, [-48,112], mult of 16
    u64 sl_lo = (L < 64) ? (H << (L & 63)) : 0;
    u64 hi_a  = (L == 0) ? 0 : (H >> ((64 - L) & 63));
    u64 hi_b  = H << ((L - 64) & 63);
    u64 sl_hi = (L < 64) ? hi_a : hi_b;
    u64 sr    = H >> ((-L) & 63);
    u64 B0 = (L >= 0) ? sl_lo : sr;                      // window halves 0..3
    u64 B1 = (L >= 0) ? sl_hi : 0;                       // window halves 4..7
    u64    R0 = (B0 << 16) | (u64)pk(s, 0.0f);           // [silu, b0, b1, b2]
    u64    R1 = (B0 >> 48) | (B1 << 16);                 // [b3, b4, b5, b6]
    uint_t R2 = (uint_t)(B1 >> 48);                      // [b7, 0]
    *(uint2*)(p)      = make_uint2((uint_t)R0, (uint_t)(R0 >> 32));
    *(uint2*)(p + 4)  = make_uint2((uint_t)R1, (uint_t)(R1 >> 32));
    *(uint_t*)(p + 8) = R2;
}

struct Rec { h2 a[5]; };
__device__ __forceinline__ Rec load_rec(const _Float16* p) {
    uint2  u0 = *(const uint2*)(p);
    uint2  u1 = *(const uint2*)(p + 4);
    uint_t u2 = *(const uint_t*)(p + 8);
    Rec r;
    r.a[0] = as_h2(u0.x); r.a[1] = as_h2(u0.y);
    r.a[2] = as_h2(u1.x); r.a[3] = as_h2(u1.y);
    r.a[4] = as_h2(u2);
    return r;
}

// d_ws layout: [0)      w16: fp16 weight records, 10 halves each:
//                        W1: rec (c*9+t), 45 recs   @ half 0
//                        W2: rec (o*125+c*25+di*5+dj), 625 recs @ half 450
//                        W3: rec (o*45+c*9+di*3+dj), 90 recs    @ half 6700
//              [15360)  fcwT: float [98][200] (transposed FC weights)
#define W2_OFF 450
#define W3_OFF 6700
#define FCWT_BYTE_OFF 15360

__global__ __launch_bounds__(256) void kan_prep(
    const float* __restrict__ wb1, const float* __restrict__ ws1,
    const float* __restrict__ wb2, const float* __restrict__ ws2,
    const float* __restrict__ wb3, const float* __restrict__ ws3,
    const float* __restrict__ fcw, _Float16* __restrict__ w16,
    float* __restrict__ fcwT)
{
    int gtid = blockIdx.x * 256 + threadIdx.x;
    int gstr = gridDim.x * 256;
    for (int i = gtid; i < 760; i += gstr) {
        const float *wb, *ws; int r;
        if (i < 45)       { wb = wb1; ws = ws1; r = i; }
        else if (i < 670) { wb = wb2; ws = ws2; r = i - 45; }
        else              { wb = wb3; ws = ws3; r = i - 670; }
        _Float16* p = w16 + i * 10;
        p[0] = (_Float16)wb[r];
#pragma unroll
        for (int g = 0; g < 8; ++g) p[1 + g] = (_Float16)ws[r * 8 + g];
        p[9] = (_Float16)0.0f;
    }
    for (int i = gtid; i < 19600; i += gstr) {
        int o = i / 98, j = i % 98;
        fcwT[j * 200 + o] = fcw[i];
    }
}

// LDS: smemA (fp16 records, overlaid): t1 [784][12]=9408h | t2 [169 pos][5c][12]=10140h
//      | t3 [81 pos][5o][12]=4860h.
//      smemB float[2048] (overlaid in time): P2h fp16 [5][676]=3380h |
//      conv2 partials [5c][5o][81]=2025f | conv3 partials [5c][2o][49]=490f |
//      h3 f32 [98] @ +1024.  Total 28.5 KB -> 5 WG/CU (20 waves).
__global__ __launch_bounds__(256) void kan_fused(
    const float* __restrict__ x,      // [B,1,28,28]
    const _Float16* __restrict__ w16, // packed weights (d_ws)
    const float* __restrict__ fcwT,   // [98][200]
    const float* __restrict__ fcb,    // [200]
    float* __restrict__ out)          // [B,200]
{
    __shared__ __align__(16) _Float16 smemA[10140];
    __shared__ __align__(16) float    smemB[2048];
    _Float16* P2h   = (_Float16*)smemB;  // [c][676] halves
    float*    part2 = smemB;             // [(c*5+o)*81 + pp]
    float*    part3 = smemB;             // [(c*2+o)*49 + pp]
    float*    h3f   = smemB + 1024;      // [98]

    const int b   = blockIdx.x;
    const int tid = threadIdx.x;
    const int wv  = __builtin_amdgcn_readfirstlane(tid >> 6);  // wave id 0..3, SGPR
    const int ln  = tid & 63;

    // ---- Phase 1: transform input pixels -> t1 records -------------------
#pragma unroll 1
    for (int i = tid; i < 784; i += 256)
        write_rec(&smemA[i * 12], x[b * 784 + i]);
    __syncthreads();

    // ---- Phase 2: conv1 3x3 at every sub-position (26x26), 5 out ch ------
#pragma unroll 1
    for (int s = tid; s < 676; s += 256) {
        int y = s / 26, xx = s % 26;
        Rec r[9];
#pragma unroll
        for (int t = 0; t < 9; ++t)
            r[t] = load_rec(&smemA[((y + t / 3) * 28 + xx + t % 3) * 12]);
        float acc[5] = {0.f, 0.f, 0.f, 0.f, 0.f};
#pragma unroll
        for (int t = 0; t < 9; ++t) {
#pragma unroll
            for (int c = 0; c < 5; ++c) {
                const h2* w = (const h2*)(w16 + (c * 9 + t) * 10);
                float a = acc[c];
#pragma unroll
                for (int q = 0; q < 5; ++q) a = fdot2f(r[t].a[q], w[q], a);
                acc[c] = a;
            }
        }
#pragma unroll
        for (int c = 0; c < 5; ++c) P2h[c * 676 + s] = (_Float16)acc[c];
    }
    __syncthreads();

    // ---- Phase 3: maxpool2 + transform -> t2 records ---------------------
#pragma unroll 1
    for (int i = tid; i < 845; i += 256) {
        int c = i / 169, pp = i % 169;
        int ph = pp / 13, pw = pp % 13;
        const _Float16* q = P2h + c * 676 + (2 * ph) * 26 + 2 * pw;
        h2 a = as_h2(*(const uint_t*)q);
        h2 d = as_h2(*(const uint_t*)(q + 26));
        float m = fmaxf(fmaxf((float)a[0], (float)a[1]),
                        fmaxf((float)d[0], (float)d[1]));
        write_rec(&smemA[pp * 60 + c * 12], m);
    }
    __syncthreads();

    // ---- Phase 4: conv2 5x5, input channel c spread over waves -----------
    // wave w -> c=w; wave 0 additionally c=4. Issue total unchanged (6250
    // wave-dot2/WG) but the serial pole drops 3125 -> 2500 and all 4 waves work.
#pragma unroll 1
    for (int c = wv; c < 5; c += 4) {
#pragma unroll 1
        for (int pp = ln; pp < 81; pp += 64) {
            int y = pp / 9, xx = pp % 9;
            float acc[5] = {0.f, 0.f, 0.f, 0.f, 0.f};
#pragma unroll 1
            for (int di = 0; di < 5; ++di) {
                const _Float16* base = &smemA[((y + di) * 13 + xx) * 60 + c * 12];
                Rec r[5];
#pragma unroll
                for (int p = 0; p < 5; ++p) r[p] = load_rec(base + p * 60);
#pragma unroll
                for (int o = 0; o < 5; ++o) {
                    const h2* w = (const h2*)(w16 + (W2_OFF + (o * 125 + c * 25 + di * 5) * 10));
                    float a = acc[o];
#pragma unroll
                    for (int dj = 0; dj < 5; ++dj)
#pragma unroll
                        for (int q = 0; q < 5; ++q)
                            a = fdot2f(r[dj].a[q], w[dj * 5 + q], a);
                    acc[o] = a;
                }
            }
#pragma unroll
            for (int o = 0; o < 5; ++o) part2[(c * 5 + o) * 81 + pp] = acc[o];
        }
    }
    __syncthreads();

    // ---- Phase 4b: c-reduce + transform -> t3 records (t2 dead) ----------
#pragma unroll 1
    for (int i = tid; i < 405; i += 256) {
        int o = i / 81, pp = i % 81;
        float v = part2[(0 * 5 + o) * 81 + pp] + part2[(1 * 5 + o) * 81 + pp]
                + part2[(2 * 5 + o) * 81 + pp] + part2[(3 * 5 + o) * 81 + pp]
                + part2[(4 * 5 + o) * 81 + pp];
        write_rec(&smemA[pp * 60 + o * 12], v);
    }
    __syncthreads();

    // ---- Phase 5: conv3 3x3, input channel c spread over waves -----------
#pragma unroll 1
    for (int c = wv; c < 5; c += 4) {
        if (ln < 49) {
            int pp = ln;
            int y = pp / 7, xx = pp % 7;
            float acc[2] = {0.f, 0.f};
#pragma unroll 1
            for (int di = 0; di < 3; ++di) {
                const _Float16* base = &smemA[((y + di) * 9 + xx) * 60 + c * 12];
                Rec r[3];
#pragma unroll
                for (int p = 0; p < 3; ++p) r[p] = load_rec(base + p * 60);
#pragma unroll
                for (int o = 0; o < 2; ++o) {
                    const h2* w = (const h2*)(w16 + (W3_OFF + (o * 45 + c * 9 + di * 3) * 10));
                    float a = acc[o];
#pragma unroll
                    for (int dj = 0; dj < 3; ++dj)
#pragma unroll
                        for (int q = 0; q < 5; ++q)
                            a = fdot2f(r[dj].a[q], w[dj * 5 + q], a);
                    acc[o] = a;
                }
            }
            part3[(c * 2 + 0) * 49 + pp] = acc[0];
            part3[(c * 2 + 1) * 49 + pp] = acc[1];
        }
    }
    __syncthreads();

    // ---- Phase 5b: c-reduce -> h3 [98] -----------------------------------
    if (tid < 98) {
        int o = tid / 49, pp = tid % 49;
        float v = part3[(0 * 2 + o) * 49 + pp] + part3[(1 * 2 + o) * 49 + pp]
                + part3[(2 * 2 + o) * 49 + pp] + part3[(3 * 2 + o) * 49 + pp]
                + part3[(4 * 2 + o) * 49 + pp];
        h3f[tid] = v;
    }
    __syncthreads();

    // ---- Phase 6: FC [98] -> [200], 2 independent chains (in-order ILP) --
    if (tid < 200) {
        float a0 = 0.f, a1 = 0.f;
#pragma unroll 7
        for (int j = 0; j < 98; j += 2) {
            a0 += fcwT[j * 200 + tid]       * h3f[j];       // h3f: broadcast
            a1 += fcwT[(j + 1) * 200 + tid] * h3f[j + 1];
        }
        out[b * 200 + tid] = fcb[tid] + a0 + a1;
    }
}

extern "C" void kernel_launch(void* const* d_in, const int* in_sizes, int n_in,
                              void* d_out, int out_size, void* d_ws, size_t ws_size,
                              hipStream_t stream) {
    const float* x   = (const float*)d_in[0];
    const float* wb1 = (const float*)d_in[1];
    const float* ws1 = (const float*)d_in[2];
    const float* wb2 = (const float*)d_in[3];
    const float* ws2 = (const float*)d_in[4];
    const float* wb3 = (const float*)d_in[5];
    const float* ws3 = (const float*)d_in[6];
    const float* fcw = (const float*)d_in[7];
    const float* fcb = (const float*)d_in[8];
    float* out = (float*)d_out;

    _Float16* w16  = (_Float16*)d_ws;
    float*    fcwT = (float*)((char*)d_ws + FCWT_BYTE_OFF);

    kan_prep<<<32, 256, 0, stream>>>(wb1, ws1, wb2, ws2, wb3, ws3, fcw, w16, fcwT);

    int B = in_sizes[0] / 784;  // 4096
    kan_fused<<<B, 256, 0, stream>>>(x, w16, fcwT, fcb, out);
}

// Round 3
// 156.337 us; speedup vs baseline: 1.7735x; 1.3229x over previous
//
#include <hip/hip_runtime.h>

// KAN conv feature extractor, fully fused: one workgroup (256 thr) per batch element.
// conv1 3x3 (1->5) + maxpool2 -> conv2 5x5 (5->5) -> conv3 3x3 (5->2) -> FC(98->200)
// Activations in LDS as fp16 "records" of 16 halves: [silu, B0..B7, 0, 0..0].
// R3: conv1 and conv2 moved to MFMA (v_mfma_f32_16x16x32_f16) -- the matrix pipe
// was idle (MfmaUtil=0) while VALU was the bottleneck (VALUBusy 78%).
//   A-frag: lane row = lane&15, k = (lane>>4)*8 + j  (one ds_read_b128 / lane / MFMA)
//   B-frag: lane col = lane&15, same k mapping; weights pre-packed K-major in d_ws
//   C/D   : col = lane&15 (out ch), row = (lane>>4)*4 + reg (position)
// K padding uses ZERO WEIGHTS with clamped (finite) A reads -- never 0*Inf.
// conv3 (small) stays on v_dot2; transforms (closed-form cardinal B-spline) on VALU.

typedef _Float16 h2 __attribute__((ext_vector_type(2)));
typedef _Float16 f16x8 __attribute__((ext_vector_type(8)));
typedef float f32x4 __attribute__((ext_vector_type(4)));
typedef unsigned int uint_t;
typedef unsigned long long u64;

__device__ __forceinline__ h2 as_h2(uint_t u) { union { uint_t u; h2 h; } c; c.u = u; return c.h; }
__device__ __forceinline__ uint_t pk(float a, float b) {
    h2 v; v[0] = (_Float16)a; v[1] = (_Float16)b;
    union { h2 h; uint_t u; } c; c.h = v; return c.u;
}

__device__ __forceinline__ float fdot2f(h2 a, h2 b, float c) {
#if __has_builtin(__builtin_amdgcn_fdot2)
    return __builtin_amdgcn_fdot2(a, b, c, false);
#else
    return c + (float)a[0] * (float)b[0] + (float)a[1] * (float)b[1];
#endif
}

__device__ __forceinline__ float silu_f(float v) {
    return v / (1.0f + __expf(-v));
}

// Transform value v -> fp16 record [silu, B0..B7, 0, 0,0,0,0,0,0] (16 halves).
// Uniform-knot cubic B-spline, grid[j] = (j-3)*0.4 - 1; only 4 bases nonzero.
__device__ __forceinline__ void write_rec16(_Float16* p, float v) {
    float s  = silu_f(v);
    float t  = (v + 2.2f) * 2.5f;
    float cf = floorf(t);
    int   c  = (int)cf;
    float u  = t - cf;
    float u2 = u * u, u3 = u2 * u;
    float w  = 1.0f - u;
    const float k6 = 0.16666667f;
    float n0 = k6 * u3;
    float n1 = k6 * (-3.0f * u3 + 3.0f * u2 + 3.0f * u + 1.0f);
    float n2 = k6 * (3.0f * u3 - 6.0f * u2 + 4.0f);
    float n3 = k6 * (w * w * w);
    u64 H = ((u64)pk(n1, n0) << 32) | (u64)pk(n3, n2);   // halves [n3,n2,n1,n0]
    if ((unsigned)c > 10u) H = 0;                        // outside [-2.2,2.2): zero bases
    int cc = c < 0 ? 0 : (c > 10 ? 10 : c);
    int L  = cc * 16 - 48;                               // window shift, mult of 16
    u64 sl_lo = (L < 64) ? (H << (L & 63)) : 0;
    u64 hi_a  = (L == 0) ? 0 : (H >> ((64 - L) & 63));
    u64 hi_b  = H << ((L - 64) & 63);
    u64 sl_hi = (L < 64) ? hi_a : hi_b;
    u64 sr    = H >> ((-L) & 63);
    u64 B0 = (L >= 0) ? sl_lo : sr;                      // window halves 0..3
    u64 B1 = (L >= 0) ? sl_hi : 0;                       // window halves 4..7
    u64    R0 = (B0 << 16) | (u64)pk(s, 0.0f);           // [silu, b0, b1, b2]
    u64    R1 = (B0 >> 48) | (B1 << 16);                 // [b3, b4, b5, b6]
    uint_t R2 = (uint_t)(B1 >> 48);                      // [b7, 0]
    uint4 lo, hi;
    lo.x = (uint_t)R0; lo.y = (uint_t)(R0 >> 32);
    lo.z = (uint_t)R1; lo.w = (uint_t)(R1 >> 32);
    hi.x = R2; hi.y = 0; hi.z = 0; hi.w = 0;
    *(uint4*)(p)     = lo;                               // halves 0-7
    *(uint4*)(p + 8) = hi;                               // halves 8-15 (tail zeros)
}

struct Rec { h2 a[5]; };
__device__ __forceinline__ Rec load_rec16(const _Float16* p) {
    uint4  u0 = *(const uint4*)(p);      // halves 0-7
    uint_t u2 = *(const uint_t*)(p + 8); // halves 8-9
    Rec r;
    r.a[0] = as_h2(u0.x); r.a[1] = as_h2(u0.y);
    r.a[2] = as_h2(u0.z); r.a[3] = as_h2(u0.w);
    r.a[4] = as_h2(u2);
    return r;
}

// d_ws layout (bytes):
//   [0)      w16 : fp16 10-half records (W1/W2/W3 as before; only W3 used by fused now)
//   [15360)  fcwT: float [98][200]
//   [93760)  w1col: fp16 [6][160]  conv1 K-major cols (row5 = zeros; K: 10 recs x16,
//                                  rec t=0..8 real -> [wb, ws0..7, 0..0], t=9 zero)
//   [95680)  w2col: fp16 [6][2400] conv2 K-major cols (row5 = zeros; K order:
//                                  ((c*5+di)*6+dj)*16+f, dj=5 pad zero, f>=10 zero)
#define W3_OFF 6700
#define FCWT_BYTE_OFF  15360
#define W1COL_BYTE_OFF 93760
#define W2COL_BYTE_OFF 95680

__global__ __launch_bounds__(256) void kan_prep(
    const float* __restrict__ wb1, const float* __restrict__ ws1,
    const float* __restrict__ wb2, const float* __restrict__ ws2,
    const float* __restrict__ wb3, const float* __restrict__ ws3,
    const float* __restrict__ fcw, _Float16* __restrict__ w16,
    float* __restrict__ fcwT)
{
    _Float16* w1col = (_Float16*)((char*)w16 + W1COL_BYTE_OFF);
    _Float16* w2col = (_Float16*)((char*)w16 + W2COL_BYTE_OFF);
    int gtid = blockIdx.x * 256 + threadIdx.x;
    int gstr = gridDim.x * 256;
    for (int i = gtid; i < 760; i += gstr) {
        const float *wb, *ws; int r;
        if (i < 45)       { wb = wb1; ws = ws1; r = i; }
        else if (i < 670) { wb = wb2; ws = ws2; r = i - 45; }
        else              { wb = wb3; ws = ws3; r = i - 670; }
        _Float16* p = w16 + i * 10;
        p[0] = (_Float16)wb[r];
#pragma unroll
        for (int g = 0; g < 8; ++g) p[1 + g] = (_Float16)ws[r * 8 + g];
        p[9] = (_Float16)0.0f;
    }
    for (int i = gtid; i < 19600; i += gstr) {
        int o = i / 98, j = i % 98;
        fcwT[j * 200 + o] = fcw[i];
    }
    for (int i = gtid; i < 960; i += gstr) {          // w1col [6][160]
        int n = i / 160, k = i % 160;
        int rec = k >> 4, f = k & 15;
        float v = 0.f;
        if (n < 5 && rec < 9 && f < 10)
            v = (f == 0) ? wb1[n * 9 + rec] : ws1[(n * 9 + rec) * 8 + (f - 1)];
        w1col[i] = (_Float16)v;
    }
    for (int i = gtid; i < 14400; i += gstr) {        // w2col [6][2400]
        int n = i / 2400, k = i % 2400;
        int R = k >> 4, f = k & 15;
        int c = R / 30, rem = R % 30, di = rem / 6, dj = rem % 6;
        float v = 0.f;
        if (n < 5 && dj < 5 && f < 10) {
            int r = n * 125 + c * 25 + di * 5 + dj;
            v = (f == 0) ? wb2[r] : ws2[r * 8 + (f - 1)];
        }
        w2col[i] = (_Float16)v;
    }
}

// LDS: smemA fp16[13600] (overlaid in time):
//   t1 [784][16]=12544h | t2 [170 pos][5c][16]=13600h (pos169 = zero rec, K-pad target)
//   | t3 [81 pos][5o][16]=6480h.
// smemB float[2048] (overlaid): P2h fp16 [5][676]=3380h | conv2 partials
//   [4w][5o][81]=1620f | conv3 partials [5c][2o][49]=490f | h3 f32 [98] @ +1024.
// Total 35392 B -> 4 WG/CU (16 waves).
__global__ __launch_bounds__(256) void kan_fused(
    const float* __restrict__ x,        // [B,1,28,28]
    const _Float16* __restrict__ w16,   // 10-half records (conv3)
    const _Float16* __restrict__ w1col, // [6][160]
    const _Float16* __restrict__ w2col, // [6][2400]
    const float* __restrict__ fcwT,     // [98][200]
    const float* __restrict__ fcb,      // [200]
    float* __restrict__ out)            // [B,200]
{
    __shared__ __align__(16) _Float16 smemA[13600];
    __shared__ __align__(16) float    smemB[2048];
    _Float16* P2h   = (_Float16*)smemB;  // [c][676] halves
    float*    part2 = smemB;             // [(w*5+o)*81 + pp]
    float*    part3 = smemB;             // [(c*2+o)*49 + pp]
    float*    h3f   = smemB + 1024;      // [98]

    const int b   = blockIdx.x;
    const int tid = threadIdx.x;
    const int wv  = __builtin_amdgcn_readfirstlane(tid >> 6);  // wave id 0..3
    const int ln  = tid & 63;

    // MFMA lane decomposition (shared by conv1/conv2)
    const int m   = ln & 15;        // A-row (position) when loading A; C-col (out ch)
    const int kb  = ln >> 4;        // k-block 0..3: k = kb*8 + j
    const int hr  = kb >> 1;        // which record of the kstep's pair
    const int s8  = (kb & 1) * 8;   // half offset within record
    const int nn  = m < 5 ? m : 5;  // B column (row 5 of w*col = zeros)

    // ---- Phase 1: transform input pixels -> t1 records -------------------
#pragma unroll 1
    for (int i = tid; i < 784; i += 256)
        write_rec16(&smemA[i * 16], x[b * 784 + i]);
    __syncthreads();

    // ---- Phase 2: conv1 3x3 via MFMA: M=676 (43 tiles), N=5(->16), K=160 -
    {
        f16x8 Bf[5];
#pragma unroll
        for (int ks = 0; ks < 5; ++ks)
            Bf[ks] = *(const f16x8*)(w1col + nn * 160 + ks * 32 + kb * 8);
        // record offsets (half units, =rec_index*16) for taps t=0..8; t=9 pad -> 0
        // rec_index(t) = (t/3)*28 + t%3
        const int offT[10] = {0, 16, 32, 448, 464, 480, 896, 912, 928, 0};
#pragma unroll 1
        for (int tile = wv; tile < 43; tile += 4) {
            int p = tile * 16 + m; p = p > 675 ? 675 : p;   // clamp: finite A for M-pad
            int y = p / 26, xx = p % 26;
            int basep = (y * 28 + xx) * 16 + s8;
            f32x4 acc = {0.f, 0.f, 0.f, 0.f};
#pragma unroll
            for (int ks = 0; ks < 5; ++ks) {
                int sel = hr ? offT[2 * ks + 1] : offT[2 * ks];
                f16x8 av = *(const f16x8*)(smemA + basep + sel);
                acc = __builtin_amdgcn_mfma_f32_16x16x32_f16(av, Bf[ks], acc, 0, 0, 0);
            }
            int srow = tile * 16 + (ln >> 4) * 4;           // C row base
#pragma unroll
            for (int r = 0; r < 4; ++r) {
                int s = srow + r;
                if (m < 5 && s < 676) P2h[m * 676 + s] = (_Float16)acc[r];
            }
        }
    }
    __syncthreads();

    // ---- Phase 3: maxpool2 + transform -> t2 records; zero pos 169 -------
#pragma unroll 1
    for (int i = tid; i < 845; i += 256) {
        int c = i / 169, pp = i % 169;
        int ph = pp / 13, pw = pp % 13;
        const _Float16* q = P2h + c * 676 + (2 * ph) * 26 + 2 * pw;
        h2 a = as_h2(*(const uint_t*)q);
        h2 d = as_h2(*(const uint_t*)(q + 26));
        float mx = fmaxf(fmaxf((float)a[0], (float)a[1]),
                         fmaxf((float)d[0], (float)d[1]));
        write_rec16(&smemA[pp * 80 + c * 16], mx);
    }
    if (tid < 10) {  // zero record row at pos 169 (K-pad reads land here: 0 * w = 0)
        uint4 z; z.x = 0; z.y = 0; z.z = 0; z.w = 0;
        *(uint4*)(&smemA[13520 + tid * 8]) = z;
    }
    __syncthreads();

    // ---- Phase 4: conv2 5x5 via MFMA: M=81 (6 tiles), N=5(->16), K=2400 --
    // K split over waves by (c,di) pair (wave w: pairs w,w+4,...); per-wave
    // private acc, 4-way LDS reduce in phase 4b. kstep = 2 records (dj pair).
    {
        int ryb[6];
#pragma unroll
        for (int t = 0; t < 6; ++t) {
            int p = t * 16 + m; p = p > 80 ? 80 : p;        // clamp: finite A for M-pad
            ryb[t] = (p / 9) * 13 + (p % 9);
        }
        f32x4 acc[6];
#pragma unroll
        for (int t = 0; t < 6; ++t) { f32x4 z = {0.f,0.f,0.f,0.f}; acc[t] = z; }
#pragma unroll 1
        for (int pr = wv; pr < 25; pr += 4) {
            int c = pr / 5, di = pr % 5;                    // wave-uniform
            const _Float16* wrow = w2col + nn * 2400 + pr * 96 + kb * 8;
            int cbase = c * 16 + s8;
            int rb = di * 13;
#pragma unroll
            for (int ks = 0; ks < 3; ++ks) {
                f16x8 bv = *(const f16x8*)(wrow + ks * 32);
                int rp_off = rb + 2 * ks + hr;              // dj = 2ks + hr (5 = pad->pos169)
#pragma unroll
                for (int t = 0; t < 6; ++t) {
                    int rp = ryb[t] + rp_off;
                    f16x8 av = *(const f16x8*)(smemA + rp * 80 + cbase);
                    acc[t] = __builtin_amdgcn_mfma_f32_16x16x32_f16(av, bv, acc[t], 0, 0, 0);
                }
            }
        }
        int prow = (ln >> 4) * 4;
#pragma unroll
        for (int t = 0; t < 6; ++t) {
#pragma unroll
            for (int r = 0; r < 4; ++r) {
                int pp = t * 16 + prow + r;
                if (m < 5 && pp < 81) part2[(wv * 5 + m) * 81 + pp] = acc[t][r];
            }
        }
    }
    __syncthreads();

    // ---- Phase 4b: 4-wave reduce + transform -> t3 records ---------------
#pragma unroll 1
    for (int i = tid; i < 405; i += 256) {
        int o = i / 81, pp = i % 81;
        float v = part2[(0 * 5 + o) * 81 + pp] + part2[(1 * 5 + o) * 81 + pp]
                + part2[(2 * 5 + o) * 81 + pp] + part2[(3 * 5 + o) * 81 + pp];
        write_rec16(&smemA[pp * 80 + o * 16], v);
    }
    __syncthreads();

    // ---- Phase 5: conv3 3x3 (dot2), input channel c spread over waves ----
#pragma unroll 1
    for (int c = wv; c < 5; c += 4) {
        if (ln < 49) {
            int pp = ln;
            int y = pp / 7, xx = pp % 7;
            float acc[2] = {0.f, 0.f};
#pragma unroll 1
            for (int di = 0; di < 3; ++di) {
                const _Float16* base = &smemA[((y + di) * 9 + xx) * 80 + c * 16];
                Rec r[3];
#pragma unroll
                for (int p = 0; p < 3; ++p) r[p] = load_rec16(base + p * 80);
#pragma unroll
                for (int o = 0; o < 2; ++o) {
                    const h2* w = (const h2*)(w16 + (W3_OFF + (o * 45 + c * 9 + di * 3) * 10));
                    float a = acc[o];
#pragma unroll
                    for (int dj = 0; dj < 3; ++dj)
#pragma unroll
                        for (int q = 0; q < 5; ++q)
                            a = fdot2f(r[dj].a[q], w[dj * 5 + q], a);
                    acc[o] = a;
                }
            }
            part3[(c * 2 + 0) * 49 + pp] = acc[0];
            part3[(c * 2 + 1) * 49 + pp] = acc[1];
        }
    }
    __syncthreads();

    // ---- Phase 5b: c-reduce -> h3 [98] -----------------------------------
    if (tid < 98) {
        int o = tid / 49, pp = tid % 49;
        float v = part3[(0 * 2 + o) * 49 + pp] + part3[(1 * 2 + o) * 49 + pp]
                + part3[(2 * 2 + o) * 49 + pp] + part3[(3 * 2 + o) * 49 + pp]
                + part3[(4 * 2 + o) * 49 + pp];
        h3f[tid] = v;
    }
    __syncthreads();

    // ---- Phase 6: FC [98] -> [200], 2 independent chains -----------------
    if (tid < 200) {
        float a0 = 0.f, a1 = 0.f;
#pragma unroll 7
        for (int j = 0; j < 98; j += 2) {
            a0 += fcwT[j * 200 + tid]       * h3f[j];       // h3f: broadcast
            a1 += fcwT[(j + 1) * 200 + tid] * h3f[j + 1];
        }
        out[b * 200 + tid] = fcb[tid] + a0 + a1;
    }
}

extern "C" void kernel_launch(void* const* d_in, const int* in_sizes, int n_in,
                              void* d_out, int out_size, void* d_ws, size_t ws_size,
                              hipStream_t stream) {
    const float* x   = (const float*)d_in[0];
    const float* wb1 = (const float*)d_in[1];
    const float* ws1 = (const float*)d_in[2];
    const float* wb2 = (const float*)d_in[3];
    const float* ws2 = (const float*)d_in[4];
    const float* wb3 = (const float*)d_in[5];
    const float* ws3 = (const float*)d_in[6];
    const float* fcw = (const float*)d_in[7];
    const float* fcb = (const float*)d_in[8];
    float* out = (float*)d_out;

    _Float16* w16   = (_Float16*)d_ws;
    float*    fcwT  = (float*)((char*)d_ws + FCWT_BYTE_OFF);
    _Float16* w1col = (_Float16*)((char*)d_ws + W1COL_BYTE_OFF);
    _Float16* w2col = (_Float16*)((char*)d_ws + W2COL_BYTE_OFF);

    kan_prep<<<32, 256, 0, stream>>>(wb1, ws1, wb2, ws2, wb3, ws3, fcw, w16, fcwT);

    int B = in_sizes[0] / 784;  // 4096
    kan_fused<<<B, 256, 0, stream>>>(x, w16, w1col, w2col, fcwT, fcb, out);
}

// Round 4
// 148.411 us; speedup vs baseline: 1.8682x; 1.0534x over previous
//
#include <hip/hip_runtime.h>

// KAN conv feature extractor, fully fused: one workgroup (256 thr) per batch element.
// conv1 3x3 (1->5) + maxpool2 -> conv2 5x5 (5->5) -> conv3 3x3 (5->2) -> FC(98->200)
// R4: (a) channel-packed conv2 K (5c x 10f = 50 real halves per position, pad to 64)
//     -> 300 MFMAs instead of 450, wave-split by (di,dj) tap;
//     (b) t2 position stride 72 halves (144B): bank stride 4 -> ~2-way (free);
//     (c) t1 XOR swizzle (chunk ^ pixel-bit2): conv1 A-reads 4-way -> 2-way;
//     (d) LDS 35.8KB -> 31.9KB -> 5 WG/CU (20 waves).
// K/M padding always multiplies ZERO WEIGHTS against FINITE activations (never 0*Inf:
// t2 pad halves are stale t1 fp16 values, written in phase 1, hence finite).

typedef _Float16 h2 __attribute__((ext_vector_type(2)));
typedef _Float16 f16x8 __attribute__((ext_vector_type(8)));
typedef float f32x4 __attribute__((ext_vector_type(4)));
typedef unsigned int uint_t;
typedef unsigned long long u64;

__device__ __forceinline__ h2 as_h2(uint_t u) { union { uint_t u; h2 h; } c; c.u = u; return c.h; }
__device__ __forceinline__ uint_t pk(float a, float b) {
    h2 v; v[0] = (_Float16)a; v[1] = (_Float16)b;
    union { h2 h; uint_t u; } c; c.h = v; return c.u;
}

__device__ __forceinline__ float fdot2f(h2 a, h2 b, float c) {
#if __has_builtin(__builtin_amdgcn_fdot2)
    return __builtin_amdgcn_fdot2(a, b, c, false);
#else
    return c + (float)a[0] * (float)b[0] + (float)a[1] * (float)b[1];
#endif
}

__device__ __forceinline__ float silu_f(float v) {
    return v / (1.0f + __expf(-v));
}

// Record words for value v: halves [silu, b0..b7, 0] as R0(4h), R1(4h), R2(2h).
// Uniform-knot cubic B-spline, grid[j] = (j-3)*0.4 - 1; only 4 bases nonzero.
struct RecW { u64 R0, R1; uint_t R2; };
__device__ __forceinline__ RecW rec_words(float v) {
    float s  = silu_f(v);
    float t  = (v + 2.2f) * 2.5f;
    float cf = floorf(t);
    int   c  = (int)cf;
    float u  = t - cf;
    float u2 = u * u, u3 = u2 * u;
    float w  = 1.0f - u;
    const float k6 = 0.16666667f;
    float n0 = k6 * u3;
    float n1 = k6 * (-3.0f * u3 + 3.0f * u2 + 3.0f * u + 1.0f);
    float n2 = k6 * (3.0f * u3 - 6.0f * u2 + 4.0f);
    float n3 = k6 * (w * w * w);
    u64 H = ((u64)pk(n1, n0) << 32) | (u64)pk(n3, n2);   // halves [n3,n2,n1,n0]
    if ((unsigned)c > 10u) H = 0;                        // outside [-2.2,2.2): zero bases
    int cc = c < 0 ? 0 : (c > 10 ? 10 : c);
    int L  = cc * 16 - 48;                               // window shift, mult of 16
    u64 sl_lo = (L < 64) ? (H << (L & 63)) : 0;
    u64 hi_a  = (L == 0) ? 0 : (H >> ((64 - L) & 63));
    u64 hi_b  = H << ((L - 64) & 63);
    u64 sl_hi = (L < 64) ? hi_a : hi_b;
    u64 sr    = H >> ((-L) & 63);
    u64 B0 = (L >= 0) ? sl_lo : sr;                      // window halves 0..3
    u64 B1 = (L >= 0) ? sl_hi : 0;                       // window halves 4..7
    RecW r;
    r.R0 = (B0 << 16) | (u64)pk(s, 0.0f);                // [silu, b0, b1, b2]
    r.R1 = (B0 >> 48) | (B1 << 16);                      // [b3, b4, b5, b6]
    r.R2 = (uint_t)(B1 >> 48);                           // [b7, 0]
    return r;
}

// 16-half record (halves 10-15 zeroed) with XOR-swizzled 16B chunks.
// off in halves (0 or 8): chunk0 -> p+(0^off), chunk1 -> p+(8^off).
__device__ __forceinline__ void write_rec16s(_Float16* p, int off, float v) {
    RecW rw = rec_words(v);
    uint4 lo, hi;
    lo.x = (uint_t)rw.R0; lo.y = (uint_t)(rw.R0 >> 32);
    lo.z = (uint_t)rw.R1; lo.w = (uint_t)(rw.R1 >> 32);
    hi.x = rw.R2; hi.y = 0; hi.z = 0; hi.w = 0;
    *(uint4*)(p + off)       = lo;                       // halves 0-7
    *(uint4*)(p + (8 ^ off)) = hi;                       // halves 8-15
}

// 10-half packed record (t2 channel-packed K): 5 dword stores, 4B-aligned.
__device__ __forceinline__ void write_rec10(_Float16* p, float v) {
    RecW rw = rec_words(v);
    uint_t* d = (uint_t*)p;
    d[0] = (uint_t)rw.R0; d[1] = (uint_t)(rw.R0 >> 32);
    d[2] = (uint_t)rw.R1; d[3] = (uint_t)(rw.R1 >> 32);
    d[4] = rw.R2;
}

struct Rec { h2 a[5]; };
__device__ __forceinline__ Rec load_rec16(const _Float16* p) {
    uint4  u0 = *(const uint4*)(p);      // halves 0-7
    uint_t u2 = *(const uint_t*)(p + 8); // halves 8-9
    Rec r;
    r.a[0] = as_h2(u0.x); r.a[1] = as_h2(u0.y);
    r.a[2] = as_h2(u0.z); r.a[3] = as_h2(u0.w);
    r.a[4] = as_h2(u2);
    return r;
}

// d_ws layout (bytes):
//   [0)      w16 : fp16 10-half records (only W3 used by fused)
//   [15360)  fcwT: float [98][200]
//   [93760)  w1col: fp16 [6][160]  conv1 K-major cols (col5 zeros; K = 10 recs x 16h,
//                                  rec t=0..8 real -> [wb, ws0..7, 0...], t=9 zero)
//   [95680)  w2col: fp16 [6][1600] conv2 tap-major cols: [tap(di*5+dj)][64h], per tap
//                                  k -> (c=k/10, f=k%10), k>=50 or f==9 -> 0
#define W3_OFF 6700
#define FCWT_BYTE_OFF  15360
#define W1COL_BYTE_OFF 93760
#define W2COL_BYTE_OFF 95680

__global__ __launch_bounds__(256) void kan_prep(
    const float* __restrict__ wb1, const float* __restrict__ ws1,
    const float* __restrict__ wb2, const float* __restrict__ ws2,
    const float* __restrict__ wb3, const float* __restrict__ ws3,
    const float* __restrict__ fcw, _Float16* __restrict__ w16,
    float* __restrict__ fcwT)
{
    _Float16* w1col = (_Float16*)((char*)w16 + W1COL_BYTE_OFF);
    _Float16* w2col = (_Float16*)((char*)w16 + W2COL_BYTE_OFF);
    int gtid = blockIdx.x * 256 + threadIdx.x;
    int gstr = gridDim.x * 256;
    for (int i = gtid; i < 760; i += gstr) {
        const float *wb, *ws; int r;
        if (i < 45)       { wb = wb1; ws = ws1; r = i; }
        else if (i < 670) { wb = wb2; ws = ws2; r = i - 45; }
        else              { wb = wb3; ws = ws3; r = i - 670; }
        _Float16* p = w16 + i * 10;
        p[0] = (_Float16)wb[r];
#pragma unroll
        for (int g = 0; g < 8; ++g) p[1 + g] = (_Float16)ws[r * 8 + g];
        p[9] = (_Float16)0.0f;
    }
    for (int i = gtid; i < 19600; i += gstr) {
        int o = i / 98, j = i % 98;
        fcwT[j * 200 + o] = fcw[i];
    }
    for (int i = gtid; i < 960; i += gstr) {          // w1col [6][160]
        int n = i / 160, k = i % 160;
        int rec = k >> 4, f = k & 15;
        float v = 0.f;
        if (n < 5 && rec < 9 && f < 10)
            v = (f == 0) ? wb1[n * 9 + rec] : ws1[(n * 9 + rec) * 8 + (f - 1)];
        w1col[i] = (_Float16)v;
    }
    for (int i = gtid; i < 9600; i += gstr) {         // w2col [6][1600] tap-major
        int n = i / 1600, k2 = i % 1600;
        int tap = k2 >> 6, k = k2 & 63;
        int di = tap / 5, dj = tap % 5;
        int c = k / 10, f = k % 10;
        float v = 0.f;
        if (n < 5 && k < 50 && f < 9) {
            int r = n * 125 + c * 25 + di * 5 + dj;
            v = (f == 0) ? wb2[r] : ws2[r * 8 + (f - 1)];
        }
        w2col[i] = (_Float16)v;
    }
}

// LDS (overlaid in time):
//   smemA fp16[12544]: t1 [784][16] (XOR-swizzled chunks) = 12544h
//                    | t2 [169 pos][72] (5c x 10h packed @ 0..49, pad 50..71) = 12168h
//                    | t3 [81 pos][5o][16] = 6480h
//   smemB f32[1696]:   P2h fp16 [5][676] = 1690f | part2 [4w][5o][81] = 1620f
//                    | part3 [5c][2o][49] = 490f | h3 [98] @ +512
// Total 31872 B -> 5 WG/CU (20 waves).
__global__ __launch_bounds__(256) void kan_fused(
    const float* __restrict__ x,        // [B,1,28,28]
    const _Float16* __restrict__ w16,   // 10-half records (conv3)
    const _Float16* __restrict__ w1col, // [6][160]
    const _Float16* __restrict__ w2col, // [6][1600]
    const float* __restrict__ fcwT,     // [98][200]
    const float* __restrict__ fcb,      // [200]
    float* __restrict__ out)            // [B,200]
{
    __shared__ __align__(16) _Float16 smemA[12544];
    __shared__ __align__(16) float    smemB[1696];
    _Float16* P2h   = (_Float16*)smemB;  // [c][676] halves
    float*    part2 = smemB;             // [(w*5+o)*81 + pp]
    float*    part3 = smemB;             // [(c*2+o)*49 + pp]
    float*    h3f   = smemB + 512;       // [98]

    const int b   = blockIdx.x;
    const int tid = threadIdx.x;
    const int wv  = __builtin_amdgcn_readfirstlane(tid >> 6);  // wave id 0..3
    const int ln  = tid & 63;

    // MFMA lane decomposition (conv1/conv2)
    const int m   = ln & 15;        // A row (position); C col (out ch)
    const int kb  = ln >> 4;        // k-block: lane k = kb*8 + j
    const int hr  = kb >> 1;        // conv1: record within kstep pair
    const int s8  = (kb & 1) * 8;   // conv1: half offset within record
    const int nn  = m < 5 ? m : 5;  // B column (col 5 = zeros)

    // ---- Phase 1: transform input pixels -> t1 records (swizzled) --------
#pragma unroll 1
    for (int i = tid; i < 784; i += 256)
        write_rec16s(&smemA[i * 16], (i & 4) << 1, x[b * 784 + i]);
    __syncthreads();

    // ---- Phase 2: conv1 3x3 via MFMA: M=676 (43 tiles), N=5(->16), K=160 -
    {
        f16x8 Bf[5];
#pragma unroll
        for (int ks = 0; ks < 5; ++ks)
            Bf[ks] = *(const f16x8*)(w1col + nn * 160 + ks * 32 + kb * 8);
        // tap t -> pixel offset; t=9 pad (zero weights, any finite A)
        const int dpix[10] = {0, 1, 2, 28, 29, 30, 56, 57, 58, 0};
#pragma unroll 1
        for (int tile = wv; tile < 43; tile += 4) {
            int p = tile * 16 + m; p = p > 675 ? 675 : p;   // M-pad: clamp (finite A)
            int pix0 = (p / 26) * 28 + (p % 26);
            f32x4 acc = {0.f, 0.f, 0.f, 0.f};
#pragma unroll
            for (int ks = 0; ks < 5; ++ks) {
                int dp = hr ? dpix[2 * ks + 1] : dpix[2 * ks];
                int p2 = pix0 + dp;
                int addr = p2 * 16 + (s8 ^ ((p2 & 4) << 1));   // match writer swizzle
                f16x8 av = *(const f16x8*)(smemA + addr);
                acc = __builtin_amdgcn_mfma_f32_16x16x32_f16(av, Bf[ks], acc, 0, 0, 0);
            }
            int srow = tile * 16 + (ln >> 4) * 4;
#pragma unroll
            for (int r = 0; r < 4; ++r) {
                int s = srow + r;
                if (m < 5 && s < 676) P2h[m * 676 + s] = (_Float16)acc[r];
            }
        }
    }
    __syncthreads();

    // ---- Phase 3: maxpool2 + transform -> t2 channel-packed records ------
#pragma unroll 1
    for (int i = tid; i < 845; i += 256) {
        int c = i / 169, pp = i % 169;
        int ph = pp / 13, pw = pp % 13;
        const _Float16* q = P2h + c * 676 + (2 * ph) * 26 + 2 * pw;
        h2 a = as_h2(*(const uint_t*)q);
        h2 d = as_h2(*(const uint_t*)(q + 26));
        float mx = fmaxf(fmaxf((float)a[0], (float)a[1]),
                         fmaxf((float)d[0], (float)d[1]));
        write_rec10(&smemA[pp * 72 + c * 10], mx);
    }
    __syncthreads();

    // ---- Phase 4: conv2 5x5 via MFMA, K channel-packed: per tap K=64 -----
    // 25 taps split over waves (7,6,6,6); per-wave private acc, reduce in 4b.
    {
        int ryb[6];
#pragma unroll
        for (int t = 0; t < 6; ++t) {
            int p = t * 16 + m; p = p > 80 ? 80 : p;        // M-pad: clamp
            ryb[t] = (p / 9) * 13 + (p % 9);
        }
        f32x4 acc[6];
#pragma unroll
        for (int t = 0; t < 6; ++t) { f32x4 z = {0.f,0.f,0.f,0.f}; acc[t] = z; }
#pragma unroll 1
        for (int tap = wv; tap < 25; tap += 4) {
            int di = tap / 5, dj = tap % 5;                 // wave-uniform
            const _Float16* wrow = w2col + nn * 1600 + tap * 64 + kb * 8;
            f16x8 bv0 = *(const f16x8*)(wrow);
            f16x8 bv1 = *(const f16x8*)(wrow + 32);
            int qoff = di * 13 + dj;
#pragma unroll
            for (int t = 0; t < 6; ++t) {
                const _Float16* ab = smemA + (ryb[t] + qoff) * 72 + kb * 8;
                acc[t] = __builtin_amdgcn_mfma_f32_16x16x32_f16(
                             *(const f16x8*)(ab), bv0, acc[t], 0, 0, 0);
                acc[t] = __builtin_amdgcn_mfma_f32_16x16x32_f16(
                             *(const f16x8*)(ab + 32), bv1, acc[t], 0, 0, 0);
            }
        }
        int prow = (ln >> 4) * 4;
#pragma unroll
        for (int t = 0; t < 6; ++t) {
#pragma unroll
            for (int r = 0; r < 4; ++r) {
                int pp = t * 16 + prow + r;
                if (m < 5 && pp < 81) part2[(wv * 5 + m) * 81 + pp] = acc[t][r];
            }
        }
    }
    __syncthreads();

    // ---- Phase 4b: 4-wave reduce + transform -> t3 records ---------------
#pragma unroll 1
    for (int i = tid; i < 405; i += 256) {
        int o = i / 81, pp = i % 81;
        float v = part2[(0 * 5 + o) * 81 + pp] + part2[(1 * 5 + o) * 81 + pp]
                + part2[(2 * 5 + o) * 81 + pp] + part2[(3 * 5 + o) * 81 + pp];
        write_rec16s(&smemA[pp * 80 + o * 16], 0, v);
    }
    __syncthreads();

    // ---- Phase 5: conv3 3x3 (dot2), input channel c spread over waves ----
#pragma unroll 1
    for (int c = wv; c < 5; c += 4) {
        if (ln < 49) {
            int pp = ln;
            int y = pp / 7, xx = pp % 7;
            float acc[2] = {0.f, 0.f};
#pragma unroll 1
            for (int di = 0; di < 3; ++di) {
                const _Float16* base = &smemA[((y + di) * 9 + xx) * 80 + c * 16];
                Rec r[3];
#pragma unroll
                for (int p = 0; p < 3; ++p) r[p] = load_rec16(base + p * 80);
#pragma unroll
                for (int o = 0; o < 2; ++o) {
                    const h2* w = (const h2*)(w16 + (W3_OFF + (o * 45 + c * 9 + di * 3) * 10));
                    float a = acc[o];
#pragma unroll
                    for (int dj = 0; dj < 3; ++dj)
#pragma unroll
                        for (int q = 0; q < 5; ++q)
                            a = fdot2f(r[dj].a[q], w[dj * 5 + q], a);
                    acc[o] = a;
                }
            }
            part3[(c * 2 + 0) * 49 + pp] = acc[0];
            part3[(c * 2 + 1) * 49 + pp] = acc[1];
        }
    }
    __syncthreads();

    // ---- Phase 5b: c-reduce -> h3 [98] -----------------------------------
    if (tid < 98) {
        int o = tid / 49, pp = tid % 49;
        float v = part3[(0 * 2 + o) * 49 + pp] + part3[(1 * 2 + o) * 49 + pp]
                + part3[(2 * 2 + o) * 49 + pp] + part3[(3 * 2 + o) * 49 + pp]
                + part3[(4 * 2 + o) * 49 + pp];
        h3f[tid] = v;
    }
    __syncthreads();

    // ---- Phase 6: FC [98] -> [200], 2 independent chains -----------------
    if (tid < 200) {
        float a0 = 0.f, a1 = 0.f;
#pragma unroll 7
        for (int j = 0; j < 98; j += 2) {
            a0 += fcwT[j * 200 + tid]       * h3f[j];       // h3f: broadcast
            a1 += fcwT[(j + 1) * 200 + tid] * h3f[j + 1];
        }
        out[b * 200 + tid] = fcb[tid] + a0 + a1;
    }
}

extern "C" void kernel_launch(void* const* d_in, const int* in_sizes, int n_in,
                              void* d_out, int out_size, void* d_ws, size_t ws_size,
                              hipStream_t stream) {
    const float* x   = (const float*)d_in[0];
    const float* wb1 = (const float*)d_in[1];
    const float* ws1 = (const float*)d_in[2];
    const float* wb2 = (const float*)d_in[3];
    const float* ws2 = (const float*)d_in[4];
    const float* wb3 = (const float*)d_in[5];
    const float* ws3 = (const float*)d_in[6];
    const float* fcw = (const float*)d_in[7];
    const float* fcb = (const float*)d_in[8];
    float* out = (float*)d_out;

    _Float16* w16   = (_Float16*)d_ws;
    float*    fcwT  = (float*)((char*)d_ws + FCWT_BYTE_OFF);
    _Float16* w1col = (_Float16*)((char*)d_ws + W1COL_BYTE_OFF);
    _Float16* w2col = (_Float16*)((char*)d_ws + W2COL_BYTE_OFF);

    kan_prep<<<32, 256, 0, stream>>>(wb1, ws1, wb2, ws2, wb3, ws3, fcw, w16, fcwT);

    int B = in_sizes[0] / 784;  // 4096
    kan_fused<<<B, 256, 0, stream>>>(x, w16, w1col, w2col, fcwT, fcb, out);
}